// Round 6
// baseline (241.999 us; speedup 1.0000x reference)
//
#include <hip/hip_runtime.h>
#include <cstddef>

#define SCALE 0.125f
#define LN_EPS 1e-6f

typedef __attribute__((ext_vector_type(8))) short bf16x8;
typedef __attribute__((ext_vector_type(4))) float f32x4;

__device__ __forceinline__ unsigned short f2bf(float f) {
    unsigned u = __float_as_uint(f);
    return (unsigned short)((u + 0x7FFFu + ((u >> 16) & 1u)) >> 16);
}
__device__ __forceinline__ unsigned pack2(float a, float b) {
    return (unsigned)f2bf(a) | ((unsigned)f2bf(b) << 16);
}
__device__ __forceinline__ float bflo(unsigned v) { return __uint_as_float(v << 16); }
__device__ __forceinline__ float bfhi(unsigned v) { return __uint_as_float(v & 0xFFFF0000u); }
__device__ __forceinline__ float bf2f(short s) { return __uint_as_float(((unsigned)(unsigned short)s) << 16); }

#define GLOAD16(gp, lp) __builtin_amdgcn_global_load_lds( \
    (const __attribute__((address_space(1))) void*)(gp),  \
    (__attribute__((address_space(3))) void*)(lp), 16, 0, 0)

// ---------------------------------------------------------------------------
// Cast all 4 weight matrices f32 -> bf16 into wb.
// ---------------------------------------------------------------------------
__global__ __launch_bounds__(256) void k_castw(
    const float* __restrict__ wqkv, const float* __restrict__ wq,
    const float* __restrict__ wkv, const float* __restrict__ wproj,
    short* __restrict__ wb)
{
    const int blk = blockIdx.x;
    const float* src; size_t so, doff;
    if (blk < 96)       { src = wqkv;  so = (size_t)blk * 2048;         doff = 0; }
    else if (blk < 128) { src = wq;    so = (size_t)(blk - 96) * 2048;  doff = 196608; }
    else if (blk < 192) { src = wkv;   so = (size_t)(blk - 128) * 2048; doff = 262144; }
    else                { src = wproj; so = (size_t)(blk - 192) * 2048; doff = 393216; }
    const size_t idx = so + (size_t)threadIdx.x * 8;
    const float4 f0 = *(const float4*)(src + idx);
    const float4 f1 = *(const float4*)(src + idx + 4);
    uint4 o;
    o.x = pack2(f0.x, f0.y); o.y = pack2(f0.z, f0.w);
    o.z = pack2(f1.x, f1.y); o.w = pack2(f1.z, f1.w);
    *(uint4*)(wb + doff + idx) = o;
}

// ---------------------------------------------------------------------------
// Cast x (16.78M f32) -> bf16. 8192 blocks x 2048 elems.
// ---------------------------------------------------------------------------
__global__ __launch_bounds__(256) void k_castx(
    const float* __restrict__ x, short* __restrict__ xb)
{
    const size_t i = ((size_t)blockIdx.x * 256 + threadIdx.x) * 8;
    const float4 f0 = *(const float4*)(x + i);
    const float4 f1 = *(const float4*)(x + i + 4);
    uint4 o;
    o.x = pack2(f0.x, f0.y); o.y = pack2(f0.z, f0.w);
    o.z = pack2(f1.x, f1.y); o.w = pack2(f1.z, f1.w);
    *(uint4*)(xb + i) = o;
}

// ---------------------------------------------------------------------------
// MFMA GEMM: C[M][ldc] = A[M][256] @ Bw[N][256]^T + bias. A, Bw bf16.
// Tile 128x128, BK=64, 4 K-tiles, double-buffered via global_load_lds
// (linear dest, XOR-swizzled source granule). 4 waves x 64x64.
// OUTMODE: 0 = f32 linear, 1 = bf16 linear,
//   2 = kv-split: cols<256 -> K row-major; cols>=256 -> V^T per (b,h)
//   3 = qkv-split: cols<512 -> qkvb[n][512]; cols>=512 (V) ->
//       vwb[((b*256+win)*4+h)*64+d][16] with win/tok from spatial pos
// ---------------------------------------------------------------------------
template<int OUTMODE>
__global__ __launch_bounds__(256, 2) void k_gemm(
    const short* __restrict__ Asrc, const short* __restrict__ Bw,
    const float* __restrict__ bias, void* __restrict__ Cdst,
    short* __restrict__ Vdst, int ldc, int nbn)
{
    __shared__ short As[2][128 * 64];
    __shared__ short Bs[2][128 * 64];

    const int tid = threadIdx.x;
    const int q8 = gridDim.x >> 3;
    const int bid = (blockIdx.x & 7) * q8 + (blockIdx.x >> 3);
    const int bm = bid / nbn, bn = bid % nbn;
    const size_t m0 = (size_t)bm * 128, n0 = (size_t)bn * 128;
    const int wid = tid >> 6, lane = tid & 63;
    const int wr = wid >> 1, wc = wid & 1;
    const int g = lane >> 4, r = lane & 15;
    const int rowc = lane >> 3, gran = lane & 7;

    f32x4 acc[4][4];
    #pragma unroll
    for (int mi = 0; mi < 4; ++mi)
        #pragma unroll
        for (int nj = 0; nj < 4; ++nj) acc[mi][nj] = (f32x4)0.f;

    auto STAGE = [&](int kt, int bufi) {
        const int k0 = kt * 64;
        #pragma unroll
        for (int i = 0; i < 4; ++i) {
            const int rbase = wid * 32 + i * 8;
            const int row = rbase + rowc;
            const int sg = gran ^ (row & 7);
            GLOAD16(Asrc + (m0 + row) * 256 + k0 + sg * 8, &As[bufi][rbase * 64]);
            GLOAD16(Bw   + (n0 + row) * 256 + k0 + sg * 8, &Bs[bufi][rbase * 64]);
        }
    };

    auto COMPUTE = [&](int bufi) {
        #pragma unroll
        for (int ks = 0; ks < 2; ++ks) {
            const int ke = ks * 32 + g * 8;
            bf16x8 a[4], b[4];
            #pragma unroll
            for (int mi = 0; mi < 4; ++mi) {
                const int row = wr * 64 + mi * 16 + r;
                a[mi] = *(const bf16x8*)&As[bufi][row * 64 + (ke ^ ((row & 7) << 3))];
            }
            #pragma unroll
            for (int nj = 0; nj < 4; ++nj) {
                const int row = wc * 64 + nj * 16 + r;
                b[nj] = *(const bf16x8*)&Bs[bufi][row * 64 + (ke ^ ((row & 7) << 3))];
            }
            #pragma unroll
            for (int mi = 0; mi < 4; ++mi)
                #pragma unroll
                for (int nj = 0; nj < 4; ++nj)
                    acc[mi][nj] = __builtin_amdgcn_mfma_f32_16x16x32_bf16(
                        a[mi], b[nj], acc[mi][nj], 0, 0, 0);
        }
    };

    STAGE(0, 0);
    __syncthreads();
    #pragma unroll
    for (int kt = 0; kt < 4; ++kt) {
        const int cur = kt & 1;
        if (kt < 3) STAGE(kt + 1, cur ^ 1);
        COMPUTE(cur);
        __syncthreads();
    }

    #pragma unroll
    for (int nj = 0; nj < 4; ++nj) {
        const size_t col = n0 + wc * 64 + nj * 16 + r;
        const float bv = bias[col];
        #pragma unroll
        for (int mi = 0; mi < 4; ++mi) {
            const size_t row = m0 + wr * 64 + mi * 16 + g * 4;
            #pragma unroll
            for (int e = 0; e < 4; ++e) {
                const float v = acc[mi][nj][e] + bv;
                const size_t rr = row + e;
                if (OUTMODE == 0) ((float*)Cdst)[rr * ldc + col] = v;
                else if (OUTMODE == 1) ((short*)Cdst)[rr * ldc + col] = (short)f2bf(v);
                else if (OUTMODE == 2) {
                    const int colk = (int)col - 256;
                    if (colk < 0) ((short*)Cdst)[rr * 256 + col] = (short)f2bf(v);
                    else {
                        const int hh = colk >> 6, dd = colk & 63;
                        Vdst[((((rr >> 8) * 4 + hh) * 64 + dd) << 8) + (rr & 255)] = (short)f2bf(v);
                    }
                } else {
                    if ((int)col < 512) ((short*)Cdst)[rr * 512 + col] = (short)f2bf(v);
                    else {
                        const int cc = (int)col - 512;
                        const int hh = cc >> 6, dd = cc & 63;
                        const int bb = (int)(rr >> 12), nn = (int)(rr & 4095);
                        const int sr = nn >> 6, sc = nn & 63;
                        const int wn = ((sr >> 2) << 4) + (sc >> 2);
                        const int tk = ((sr & 3) << 2) + (sc & 3);
                        Vdst[(((((size_t)bb * 256 + wn) * 4 + hh) * 64 + dd) << 4) + tk]
                            = (short)f2bf(v);
                    }
                }
            }
        }
    }
}

// ---------------------------------------------------------------------------
// Window attention via MFMA + residual + LN + pool. 1 window/block,
// wave = head. Q/K fragments straight from global qkvb[n][512];
// V^T fragments straight from global vwb. P in tiny LDS [16][40]
// (keys 16..31 zeroed -> K=32 PV mfma safe: A-zeros kill B-overlap reads,
// all workspace bytes are finite bf16). O -> zbuf, fused LN+pool epilogue.
// ---------------------------------------------------------------------------
__global__ __launch_bounds__(256) void k_win3(
    const short* __restrict__ qkvb, const short* __restrict__ vwb,
    const short* __restrict__ xb, const float* __restrict__ gnw,
    const float* __restrict__ gnb, short* __restrict__ lnb,
    short* __restrict__ pooledb)
{
    __shared__ float zbuf[16][260];
    __shared__ short Pb[4][16][40];

    const int tid = threadIdx.x;
    const int blk = blockIdx.x;
    const int b = blk >> 8, win = blk & 255;
    const int ghi = win >> 4, gwi = win & 15;
    const size_t nb = (size_t)b * 4096;
    const int h = tid >> 6, lane = tid & 63;
    const int g = lane >> 4, l15 = lane & 15;

    // ---- scores: S = Q K^T per head (2 MFMA), frags from global ----
    const int n15 = (ghi * 4 + (l15 >> 2)) * 64 + gwi * 4 + (l15 & 3);
    const size_t qkrow = (nb + n15) * 512;
    const bf16x8 aq0 = *(const bf16x8*)(qkvb + qkrow + h * 64 + g * 8);
    const bf16x8 aq1 = *(const bf16x8*)(qkvb + qkrow + h * 64 + 32 + g * 8);
    const bf16x8 bk0 = *(const bf16x8*)(qkvb + qkrow + 256 + h * 64 + g * 8);
    const bf16x8 bk1 = *(const bf16x8*)(qkvb + qkrow + 256 + h * 64 + 32 + g * 8);

    f32x4 acc = (f32x4)0.f;
    acc = __builtin_amdgcn_mfma_f32_16x16x32_bf16(aq0, bk0, acc, 0, 0, 0);
    acc = __builtin_amdgcn_mfma_f32_16x16x32_bf16(aq1, bk1, acc, 0, 0, 0);

    // ---- wave-parallel softmax over keys (= lane group of 16) ----
    float p[4];
    #pragma unroll
    for (int e = 0; e < 4; ++e) {
        const float s = acc[e] * SCALE;
        float mm = s;
        mm = fmaxf(mm, __shfl_xor(mm, 1)); mm = fmaxf(mm, __shfl_xor(mm, 2));
        mm = fmaxf(mm, __shfl_xor(mm, 4)); mm = fmaxf(mm, __shfl_xor(mm, 8));
        const float pe = __expf(s - mm);
        float rs = pe;
        rs += __shfl_xor(rs, 1); rs += __shfl_xor(rs, 2);
        rs += __shfl_xor(rs, 4); rs += __shfl_xor(rs, 8);
        p[e] = pe / rs;
    }
    #pragma unroll
    for (int e = 0; e < 4; ++e) {
        Pb[h][g * 4 + e][l15] = (short)f2bf(p[e]);   // row = q, col = key
        Pb[h][g * 4 + e][16 + l15] = 0;              // zero pad keys 16..31
    }
    __syncthreads();

    // ---- PV: O = P V (K=32, upper half zero), V^T frags from global ----
    const bf16x8 ap = *(const bf16x8*)&Pb[h][l15][g * 8];
    f32x4 oc[4];
    #pragma unroll
    for (int nt = 0; nt < 4; ++nt) oc[nt] = (f32x4)0.f;
    const short* vbase = vwb + ((((size_t)b * 256 + win) * 4 + h) << 10);
    #pragma unroll
    for (int nt = 0; nt < 4; ++nt) {
        const bf16x8 bv = *(const bf16x8*)(vbase + (nt * 16 + l15) * 16 + g * 8);
        oc[nt] = __builtin_amdgcn_mfma_f32_16x16x32_bf16(ap, bv, oc[nt], 0, 0, 0);
    }
    #pragma unroll
    for (int e = 0; e < 4; ++e)
        #pragma unroll
        for (int nt = 0; nt < 4; ++nt)
            zbuf[g * 4 + e][h * 64 + nt * 16 + l15] = oc[nt][e];
    __syncthreads();

    // ---- LN over 256 ch per token (+ bf16 x residual); wave h: tokens h*4.. ----
    {
        const float4 gw = ((const float4*)gnw)[lane];
        const float4 gb = ((const float4*)gnb)[lane];
        #pragma unroll
        for (int i = 0; i < 4; ++i) {
            const int t = h * 4 + i;
            const int n = (ghi * 4 + (t >> 2)) * 64 + gwi * 4 + (t & 3);
            float4 zv = *(const float4*)&zbuf[t][lane * 4];
            const short4 xv = *(const short4*)(xb + (nb + n) * 256 + lane * 4);
            zv.x += bf2f(xv.x); zv.y += bf2f(xv.y);
            zv.z += bf2f(xv.z); zv.w += bf2f(xv.w);
            float ssum = zv.x + zv.y + zv.z + zv.w;
            for (int off = 1; off < 64; off <<= 1) ssum += __shfl_xor(ssum, off);
            const float u = ssum * (1.f / 256.f);
            const float dx = zv.x - u, dy = zv.y - u, dz = zv.z - u, dw = zv.w - u;
            float vsum = dx * dx + dy * dy + dz * dz + dw * dw;
            for (int off = 1; off < 64; off <<= 1) vsum += __shfl_xor(vsum, off);
            const float rinv = rsqrtf(vsum * (1.f / 256.f) + LN_EPS);
            float4 y;
            y.x = gw.x * dx * rinv + gb.x;
            y.y = gw.y * dy * rinv + gb.y;
            y.z = gw.z * dz * rinv + gb.z;
            y.w = gw.w * dw * rinv + gb.w;
            *(float4*)&zbuf[t][lane * 4] = y;
            short4 sv;
            sv.x = (short)f2bf(y.x); sv.y = (short)f2bf(y.y);
            sv.z = (short)f2bf(y.z); sv.w = (short)f2bf(y.w);
            *(short4*)(lnb + (nb + n) * 256 + lane * 4) = sv;
        }
    }
    __syncthreads();

    // ---- 4x4 avg pool of LN output ----
    {
        float ps = 0.f;
        #pragma unroll
        for (int t = 0; t < 16; ++t) ps += zbuf[t][tid];
        pooledb[((size_t)b * 256 + win) * 256 + tid] = (short)f2bf(ps * (1.f / 16.f));
    }
}

// ---------------------------------------------------------------------------
// Pooled global attention via MFMA. 512 threads / 8 waves.
// ---------------------------------------------------------------------------
#define CP 280
__global__ __launch_bounds__(512, 1) void k_glb(
    const short* __restrict__ qgb, const short* __restrict__ kb,
    const short* __restrict__ vtb, const short* __restrict__ lnb,
    short* __restrict__ gxb)
{
    __shared__ short Ks[256 * 64];
    __shared__ short Vt[64 * 256];
    __shared__ short Pl[8][16 * CP];

    const int tid = threadIdx.x;
    const int bid = (blockIdx.x & 7) * 256 + (blockIdx.x >> 3);
    const int bh = bid >> 5, qt = bid & 31;
    const int b = bh >> 2, h = bh & 3;
    const int q0 = qt * 128;
    const size_t nb = (size_t)b * 4096;

    #pragma unroll
    for (int i = 0; i < 4; ++i) {
        const int c = i * 512 + tid;
        const int p = c >> 3, d8 = (c & 7) * 8;
        const uint4 u = *(const uint4*)(kb + ((size_t)(b * 256 + p)) * 256 + h * 64 + d8);
        *(uint4*)&Ks[p * 64 + (d8 ^ ((p & 7) << 3))] = u;
    }
    const short* vsrc = vtb + (size_t)bh * 16384;
    #pragma unroll
    for (int i = 0; i < 4; ++i) {
        const int c = i * 512 + tid;
        const int d = c >> 5, k8 = (c & 31) * 8;
        const uint4 u = *(const uint4*)(vsrc + d * 256 + k8);
        *(uint4*)&Vt[d * 256 + (k8 ^ ((d & 7) << 3))] = u;
    }
    __syncthreads();

    const int w = tid >> 6, lane = tid & 63;
    const int g = lane >> 4, l15 = lane & 15;

    bf16x8 aq[2];
    {
        const int n = q0 + w * 16 + l15;
        const short* qp = qgb + (nb + n) * 256 + h * 64 + g * 8;
        aq[0] = *(const bf16x8*)qp;
        aq[1] = *(const bf16x8*)(qp + 32);
    }

    f32x4 acc[16];
    #pragma unroll
    for (int nt = 0; nt < 16; ++nt) acc[nt] = (f32x4)0.f;

    #pragma unroll
    for (int nt = 0; nt < 16; ++nt) {
        const int key = nt * 16 + l15;
        const int sw = (key & 7) << 3;
        const bf16x8 bk0 = *(const bf16x8*)&Ks[key * 64 + ((g * 8) ^ sw)];
        const bf16x8 bk1 = *(const bf16x8*)&Ks[key * 64 + ((g * 8 + 32) ^ sw)];
        acc[nt] = __builtin_amdgcn_mfma_f32_16x16x32_bf16(aq[0], bk0, acc[nt], 0, 0, 0);
        acc[nt] = __builtin_amdgcn_mfma_f32_16x16x32_bf16(aq[1], bk1, acc[nt], 0, 0, 0);
    }

    float rs[4];
    short* Pw = &Pl[w][0];
    #pragma unroll
    for (int e = 0; e < 4; ++e) {
        const int prow = (g * 4 + e) * CP;
        float rsum = 0.f;
        #pragma unroll
        for (int nt = 0; nt < 16; ++nt) {
            const float p = __expf(acc[nt][e] * SCALE);
            rsum += p;
            Pw[prow + nt * 16 + l15] = (short)f2bf(p);
        }
        rs[e] = rsum;
    }
    #pragma unroll
    for (int e = 0; e < 4; ++e) {
        float v = rs[e];
        v += __shfl_xor(v, 1); v += __shfl_xor(v, 2);
        v += __shfl_xor(v, 4); v += __shfl_xor(v, 8);
        rs[e] = v;
    }

    f32x4 oc[4];
    #pragma unroll
    for (int nt = 0; nt < 4; ++nt) oc[nt] = (f32x4)0.f;

    #pragma unroll
    for (int ks = 0; ks < 8; ++ks) {
        const int kc = ks * 32 + g * 8;
        const bf16x8 a0 = *(const bf16x8*)&Pw[l15 * CP + kc];
        #pragma unroll
        for (int nt = 0; nt < 4; ++nt) {
            const int d = nt * 16 + l15;
            const bf16x8 bv = *(const bf16x8*)&Vt[d * 256 + (kc ^ ((d & 7) << 3))];
            oc[nt] = __builtin_amdgcn_mfma_f32_16x16x32_bf16(a0, bv, oc[nt], 0, 0, 0);
        }
    }

    #pragma unroll
    for (int e = 0; e < 4; ++e) {
        const float inv = 1.f / rs[e];
        const int n = q0 + w * 16 + g * 4 + e;
        const size_t base = (nb + n) * 256 + h * 64;
        #pragma unroll
        for (int nt = 0; nt < 4; ++nt) {
            const int d = nt * 16 + l15;
            gxb[base + d] = (short)f2bf(oc[nt][e] * inv + bf2f(lnb[base + d]));
        }
    }
}

// ---------------------------------------------------------------------------
extern "C" void kernel_launch(void* const* d_in, const int* in_sizes, int n_in,
                              void* d_out, int out_size, void* d_ws, size_t ws_size,
                              hipStream_t stream)
{
    (void)in_sizes; (void)n_in; (void)out_size; (void)ws_size;
    const float* x     = (const float*)d_in[0];
    const float* wqkv  = (const float*)d_in[1];
    const float* bqkv  = (const float*)d_in[2];
    const float* wq    = (const float*)d_in[3];
    const float* bq    = (const float*)d_in[4];
    const float* wkv   = (const float*)d_in[5];
    const float* bkv   = (const float*)d_in[6];
    const float* wproj = (const float*)d_in[7];
    const float* bproj = (const float*)d_in[8];
    const float* gnw   = (const float*)d_in[9];
    const float* gnb   = (const float*)d_in[10];
    float* out = (float*)d_out;

    char* wsb = (char*)d_ws;
    short* wb      = (short*)(wsb + 0);            // cast weights (bf16)
    short* qkvb    = (short*)(wsb + 1048576);      // 65536 x 512 (Q,K)
    short* vwb     = (short*)(wsb + 68157440);     // 16384 winh x 64 d x 16 tok
    short* lnb     = (short*)(wsb + 101711872);    // 65536 x 256
    short* qgb     = (short*)(wsb + 135266304);    // 65536 x 256
    short* kb      = (short*)(wsb + 168820736);    // 4096 x 256 (K)
    short* vtb     = (short*)(wsb + 170917888);    // 64bh x 64d x 256p (V^T)
    short* pooledb = (short*)(wsb + 173015040);    // 4096 x 256
    short* gxb     = (short*)(wsb + 175112192);    // 65536 x 256 bf16
    short* xb      = (short*)(wsb + 208666624);    // 65536 x 256 bf16 (x cast)

    k_castw<<<dim3(224),  dim3(256), 0, stream>>>(wqkv, wq, wkv, wproj, wb);
    k_castx<<<dim3(8192), dim3(256), 0, stream>>>(x, xb);
    // qkv = x @ Wqkv^T + b  (65536 x 768, K=256): Q,K -> qkvb, V -> vwb (win-T)
    k_gemm<3><<<dim3(3072), dim3(256), 0, stream>>>(xb, wb, bqkv, qkvb, vwb, 512, 6);
    // window attention + LN + pool (MFMA)
    k_win3<<<dim3(4096), dim3(256), 0, stream>>>(qkvb, vwb, xb, gnw, gnb, lnb, pooledb);
    // qg = ln @ Wq^T + b              (65536 x 256)
    k_gemm<1><<<dim3(1024), dim3(256), 0, stream>>>(lnb, wb + 196608, bq, qgb, nullptr, 256, 2);
    // kv = pooled @ Wkv^T + b, split K / V^T
    k_gemm<2><<<dim3(128), dim3(256), 0, stream>>>(pooledb, wb + 262144, bkv, kb, vtb, 512, 4);
    // pooled global attention + residual (MFMA)
    k_glb<<<dim3(2048), dim3(512), 0, stream>>>(qgb, kb, vtb, lnb, gxb);
    // out = gx @ Wproj^T + b          (65536 x 256, f32 out)
    k_gemm<0><<<dim3(1024), dim3(256), 0, stream>>>(gxb, wb + 393216, bproj, out, nullptr, 256, 2);
}

// Round 8
// 212.530 us; speedup vs baseline: 1.1387x; 1.1387x over previous
//
#include <hip/hip_runtime.h>
#include <cstddef>

#define SCALE 0.125f
#define LN_EPS 1e-6f

typedef __attribute__((ext_vector_type(8))) short bf16x8;
typedef __attribute__((ext_vector_type(4))) float f32x4;

__device__ __forceinline__ unsigned short f2bf(float f) {
    unsigned u = __float_as_uint(f);
    return (unsigned short)((u + 0x7FFFu + ((u >> 16) & 1u)) >> 16);
}
__device__ __forceinline__ unsigned pack2(float a, float b) {
    return (unsigned)f2bf(a) | ((unsigned)f2bf(b) << 16);
}
__device__ __forceinline__ float bflo(unsigned v) { return __uint_as_float(v << 16); }
__device__ __forceinline__ float bfhi(unsigned v) { return __uint_as_float(v & 0xFFFF0000u); }
__device__ __forceinline__ float bf2f(short s) { return __uint_as_float(((unsigned)(unsigned short)s) << 16); }

#define GLOAD16(gp, lp) __builtin_amdgcn_global_load_lds( \
    (const __attribute__((address_space(1))) void*)(gp),  \
    (__attribute__((address_space(3))) void*)(lp), 16, 0, 0)

// ---------------------------------------------------------------------------
// Cast all 4 weight matrices f32 -> bf16 into wb.
// ---------------------------------------------------------------------------
__global__ __launch_bounds__(256) void k_castw(
    const float* __restrict__ wqkv, const float* __restrict__ wq,
    const float* __restrict__ wkv, const float* __restrict__ wproj,
    short* __restrict__ wb)
{
    const int blk = blockIdx.x;
    const float* src; size_t so, doff;
    if (blk < 96)       { src = wqkv;  so = (size_t)blk * 2048;         doff = 0; }
    else if (blk < 128) { src = wq;    so = (size_t)(blk - 96) * 2048;  doff = 196608; }
    else if (blk < 192) { src = wkv;   so = (size_t)(blk - 128) * 2048; doff = 262144; }
    else                { src = wproj; so = (size_t)(blk - 192) * 2048; doff = 393216; }
    const size_t idx = so + (size_t)threadIdx.x * 8;
    const float4 f0 = *(const float4*)(src + idx);
    const float4 f1 = *(const float4*)(src + idx + 4);
    uint4 o;
    o.x = pack2(f0.x, f0.y); o.y = pack2(f0.z, f0.w);
    o.z = pack2(f1.x, f1.y); o.w = pack2(f1.z, f1.w);
    *(uint4*)(wb + doff + idx) = o;
}

// ---------------------------------------------------------------------------
// Cast x (16.78M f32) -> bf16. 8192 blocks x 2048 elems.
// ---------------------------------------------------------------------------
__global__ __launch_bounds__(256) void k_castx(
    const float* __restrict__ x, short* __restrict__ xb)
{
    const size_t i = ((size_t)blockIdx.x * 256 + threadIdx.x) * 8;
    const float4 f0 = *(const float4*)(x + i);
    const float4 f1 = *(const float4*)(x + i + 4);
    uint4 o;
    o.x = pack2(f0.x, f0.y); o.y = pack2(f0.z, f0.w);
    o.z = pack2(f1.x, f1.y); o.w = pack2(f1.z, f1.w);
    *(uint4*)(xb + i) = o;
}

// ---------------------------------------------------------------------------
// MFMA GEMM: C[M][ldc] = A[M][256] @ Bw[N][256]^T + bias. A, Bw bf16.
// Tile 128x128, BK=64, 4 K-tiles, double-buffered via global_load_lds
// (linear dest, XOR-swizzled source granule). 4 waves x 64x64.
// OUTMODE: 0 = f32 linear, 1 = bf16 linear,
//   2 = kv-split: cols<256 -> K row-major; cols>=256 -> V^T per (b,h)
// ---------------------------------------------------------------------------
template<int OUTMODE>
__global__ __launch_bounds__(256, 2) void k_gemm(
    const short* __restrict__ Asrc, const short* __restrict__ Bw,
    const float* __restrict__ bias, void* __restrict__ Cdst,
    short* __restrict__ Vdst, int ldc, int nbn)
{
    __shared__ short As[2][128 * 64];
    __shared__ short Bs[2][128 * 64];

    const int tid = threadIdx.x;
    const int q8 = gridDim.x >> 3;
    const int bid = (blockIdx.x & 7) * q8 + (blockIdx.x >> 3);
    const int bm = bid / nbn, bn = bid % nbn;
    const size_t m0 = (size_t)bm * 128, n0 = (size_t)bn * 128;
    const int wid = tid >> 6, lane = tid & 63;
    const int wr = wid >> 1, wc = wid & 1;
    const int g = lane >> 4, r = lane & 15;
    const int rowc = lane >> 3, gran = lane & 7;

    f32x4 acc[4][4];
    #pragma unroll
    for (int mi = 0; mi < 4; ++mi)
        #pragma unroll
        for (int nj = 0; nj < 4; ++nj) acc[mi][nj] = (f32x4)0.f;

    auto STAGE = [&](int kt, int bufi) {
        const int k0 = kt * 64;
        #pragma unroll
        for (int i = 0; i < 4; ++i) {
            const int rbase = wid * 32 + i * 8;
            const int row = rbase + rowc;
            const int sg = gran ^ (row & 7);
            GLOAD16(Asrc + (m0 + row) * 256 + k0 + sg * 8, &As[bufi][rbase * 64]);
            GLOAD16(Bw   + (n0 + row) * 256 + k0 + sg * 8, &Bs[bufi][rbase * 64]);
        }
    };

    auto COMPUTE = [&](int bufi) {
        #pragma unroll
        for (int ks = 0; ks < 2; ++ks) {
            const int ke = ks * 32 + g * 8;
            bf16x8 a[4], b[4];
            #pragma unroll
            for (int mi = 0; mi < 4; ++mi) {
                const int row = wr * 64 + mi * 16 + r;
                a[mi] = *(const bf16x8*)&As[bufi][row * 64 + (ke ^ ((row & 7) << 3))];
            }
            #pragma unroll
            for (int nj = 0; nj < 4; ++nj) {
                const int row = wc * 64 + nj * 16 + r;
                b[nj] = *(const bf16x8*)&Bs[bufi][row * 64 + (ke ^ ((row & 7) << 3))];
            }
            #pragma unroll
            for (int mi = 0; mi < 4; ++mi)
                #pragma unroll
                for (int nj = 0; nj < 4; ++nj)
                    acc[mi][nj] = __builtin_amdgcn_mfma_f32_16x16x32_bf16(
                        a[mi], b[nj], acc[mi][nj], 0, 0, 0);
        }
    };

    STAGE(0, 0);
    __syncthreads();
    #pragma unroll
    for (int kt = 0; kt < 4; ++kt) {
        const int cur = kt & 1;
        if (kt < 3) STAGE(kt + 1, cur ^ 1);
        COMPUTE(cur);
        __syncthreads();
    }

    #pragma unroll
    for (int nj = 0; nj < 4; ++nj) {
        const size_t col = n0 + wc * 64 + nj * 16 + r;
        const float bv = bias[col];
        #pragma unroll
        for (int mi = 0; mi < 4; ++mi) {
            const size_t row = m0 + wr * 64 + mi * 16 + g * 4;
            #pragma unroll
            for (int e = 0; e < 4; ++e) {
                const float v = acc[mi][nj][e] + bv;
                const size_t rr = row + e;
                if (OUTMODE == 0) ((float*)Cdst)[rr * ldc + col] = v;
                else if (OUTMODE == 1) ((short*)Cdst)[rr * ldc + col] = (short)f2bf(v);
                else {
                    const int colk = (int)col - 256;
                    if (colk < 0) ((short*)Cdst)[rr * 256 + col] = (short)f2bf(v);
                    else {
                        const int hh = colk >> 6, dd = colk & 63;
                        Vdst[((((rr >> 8) * 4 + hh) * 64 + dd) << 8) + (rr & 255)] = (short)f2bf(v);
                    }
                }
            }
        }
    }
}

// ---------------------------------------------------------------------------
// V transpose: qkvb[n][768] cols 512..767 -> vwb[((b*256+win)*4+h)*64+d][16tok].
// 1 window/block. LDS round-trip; coalesced 32B/thread output stores.
// ---------------------------------------------------------------------------
__global__ __launch_bounds__(256) void k_vtr(
    const short* __restrict__ qkvb, short* __restrict__ vwb)
{
    __shared__ short Vl[16][260];
    const int tid = threadIdx.x;
    const int blk = blockIdx.x;              // b*256 + win
    const int b = blk >> 8, win = blk & 255;
    const int ghi = win >> 4, gwi = win & 15;
    const size_t nb = (size_t)b * 4096;

    // load 16 tok x 256 ch (512 granules of 8 shorts), coalesced per token row
    #pragma unroll
    for (int i = 0; i < 2; ++i) {
        const int c = i * 256 + tid;         // 0..511
        const int tok = c >> 5, ch = c & 31;
        const int n = (ghi * 4 + (tok >> 2)) * 64 + gwi * 4 + (tok & 3);
        const uint4 u = *(const uint4*)(qkvb + (nb + n) * 768 + 512 + ch * 8);
        short* dst = &Vl[tok][ch * 8];
        *(uint2*)dst = make_uint2(u.x, u.y);
        *(uint2*)(dst + 4) = make_uint2(u.z, u.w);
    }
    __syncthreads();

    // thread = channel c = h*64+d; gather 16 tokens down the LDS column,
    // store 32B contiguous at vwb[(blk*256 + c)*16]
    unsigned w[8];
    #pragma unroll
    for (int k = 0; k < 8; ++k) {
        const unsigned lo = (unsigned)(unsigned short)Vl[2 * k][tid];
        const unsigned hi = (unsigned)(unsigned short)Vl[2 * k + 1][tid];
        w[k] = lo | (hi << 16);
    }
    short* dst = vwb + ((size_t)blk * 256 + tid) * 16;
    *(uint4*)dst = make_uint4(w[0], w[1], w[2], w[3]);
    *(uint4*)(dst + 8) = make_uint4(w[4], w[5], w[6], w[7]);
}

// ---------------------------------------------------------------------------
// Window attention via MFMA + residual + LN + pool (round-6 verified body;
// only the Q/K stride changed 512->768). 1 window/block, wave = head.
// ---------------------------------------------------------------------------
__global__ __launch_bounds__(256) void k_win3(
    const short* __restrict__ qkvb, const short* __restrict__ vwb,
    const short* __restrict__ xb, const float* __restrict__ gnw,
    const float* __restrict__ gnb, short* __restrict__ lnb,
    short* __restrict__ pooledb)
{
    __shared__ float zbuf[16][260];
    __shared__ short Pb[4][16][40];

    const int tid = threadIdx.x;
    const int blk = blockIdx.x;
    const int b = blk >> 8, win = blk & 255;
    const int ghi = win >> 4, gwi = win & 15;
    const size_t nb = (size_t)b * 4096;
    const int h = tid >> 6, lane = tid & 63;
    const int g = lane >> 4, l15 = lane & 15;

    // ---- scores: S = Q K^T per head (2 MFMA), frags from global ----
    const int n15 = (ghi * 4 + (l15 >> 2)) * 64 + gwi * 4 + (l15 & 3);
    const size_t qkrow = (nb + n15) * 768;
    const bf16x8 aq0 = *(const bf16x8*)(qkvb + qkrow + h * 64 + g * 8);
    const bf16x8 aq1 = *(const bf16x8*)(qkvb + qkrow + h * 64 + 32 + g * 8);
    const bf16x8 bk0 = *(const bf16x8*)(qkvb + qkrow + 256 + h * 64 + g * 8);
    const bf16x8 bk1 = *(const bf16x8*)(qkvb + qkrow + 256 + h * 64 + 32 + g * 8);

    f32x4 acc = (f32x4)0.f;
    acc = __builtin_amdgcn_mfma_f32_16x16x32_bf16(aq0, bk0, acc, 0, 0, 0);
    acc = __builtin_amdgcn_mfma_f32_16x16x32_bf16(aq1, bk1, acc, 0, 0, 0);

    // ---- wave-parallel softmax over keys (= lane group of 16) ----
    float p[4];
    #pragma unroll
    for (int e = 0; e < 4; ++e) {
        const float s = acc[e] * SCALE;
        float mm = s;
        mm = fmaxf(mm, __shfl_xor(mm, 1)); mm = fmaxf(mm, __shfl_xor(mm, 2));
        mm = fmaxf(mm, __shfl_xor(mm, 4)); mm = fmaxf(mm, __shfl_xor(mm, 8));
        const float pe = __expf(s - mm);
        float rs = pe;
        rs += __shfl_xor(rs, 1); rs += __shfl_xor(rs, 2);
        rs += __shfl_xor(rs, 4); rs += __shfl_xor(rs, 8);
        p[e] = pe / rs;
    }
    #pragma unroll
    for (int e = 0; e < 4; ++e) {
        Pb[h][g * 4 + e][l15] = (short)f2bf(p[e]);   // row = q, col = key
        Pb[h][g * 4 + e][16 + l15] = 0;              // zero pad keys 16..31
    }
    __syncthreads();

    // ---- PV: O = P V (K=32, upper half zero), V^T frags from global ----
    const bf16x8 ap = *(const bf16x8*)&Pb[h][l15][g * 8];
    f32x4 oc[4];
    #pragma unroll
    for (int nt = 0; nt < 4; ++nt) oc[nt] = (f32x4)0.f;
    const short* vbase = vwb + ((((size_t)b * 256 + win) * 4 + h) << 10);
    #pragma unroll
    for (int nt = 0; nt < 4; ++nt) {
        const bf16x8 bv = *(const bf16x8*)(vbase + (nt * 16 + l15) * 16 + g * 8);
        oc[nt] = __builtin_amdgcn_mfma_f32_16x16x32_bf16(ap, bv, oc[nt], 0, 0, 0);
    }
    #pragma unroll
    for (int e = 0; e < 4; ++e)
        #pragma unroll
        for (int nt = 0; nt < 4; ++nt)
            zbuf[g * 4 + e][h * 64 + nt * 16 + l15] = oc[nt][e];
    __syncthreads();

    // ---- LN over 256 ch per token (+ bf16 x residual); wave h: tokens h*4.. ----
    {
        const float4 gw = ((const float4*)gnw)[lane];
        const float4 gb = ((const float4*)gnb)[lane];
        #pragma unroll
        for (int i = 0; i < 4; ++i) {
            const int t = h * 4 + i;
            const int n = (ghi * 4 + (t >> 2)) * 64 + gwi * 4 + (t & 3);
            float4 zv = *(const float4*)&zbuf[t][lane * 4];
            const short4 xv = *(const short4*)(xb + (nb + n) * 256 + lane * 4);
            zv.x += bf2f(xv.x); zv.y += bf2f(xv.y);
            zv.z += bf2f(xv.z); zv.w += bf2f(xv.w);
            float ssum = zv.x + zv.y + zv.z + zv.w;
            for (int off = 1; off < 64; off <<= 1) ssum += __shfl_xor(ssum, off);
            const float u = ssum * (1.f / 256.f);
            const float dx = zv.x - u, dy = zv.y - u, dz = zv.z - u, dw = zv.w - u;
            float vsum = dx * dx + dy * dy + dz * dz + dw * dw;
            for (int off = 1; off < 64; off <<= 1) vsum += __shfl_xor(vsum, off);
            const float rinv = rsqrtf(vsum * (1.f / 256.f) + LN_EPS);
            float4 y;
            y.x = gw.x * dx * rinv + gb.x;
            y.y = gw.y * dy * rinv + gb.y;
            y.z = gw.z * dz * rinv + gb.z;
            y.w = gw.w * dw * rinv + gb.w;
            *(float4*)&zbuf[t][lane * 4] = y;
            short4 sv;
            sv.x = (short)f2bf(y.x); sv.y = (short)f2bf(y.y);
            sv.z = (short)f2bf(y.z); sv.w = (short)f2bf(y.w);
            *(short4*)(lnb + (nb + n) * 256 + lane * 4) = sv;
        }
    }
    __syncthreads();

    // ---- 4x4 avg pool of LN output ----
    {
        float ps = 0.f;
        #pragma unroll
        for (int t = 0; t < 16; ++t) ps += zbuf[t][tid];
        pooledb[((size_t)b * 256 + win) * 256 + tid] = (short)f2bf(ps * (1.f / 16.f));
    }
}

// ---------------------------------------------------------------------------
// Pooled global attention via MFMA. 512 threads / 8 waves.
// ---------------------------------------------------------------------------
#define CP 280
__global__ __launch_bounds__(512, 1) void k_glb(
    const short* __restrict__ qgb, const short* __restrict__ kb,
    const short* __restrict__ vtb, const short* __restrict__ lnb,
    short* __restrict__ gxb)
{
    __shared__ short Ks[256 * 64];
    __shared__ short Vt[64 * 256];
    __shared__ short Pl[8][16 * CP];

    const int tid = threadIdx.x;
    const int bid = (blockIdx.x & 7) * 256 + (blockIdx.x >> 3);
    const int bh = bid >> 5, qt = bid & 31;
    const int b = bh >> 2, h = bh & 3;
    const int q0 = qt * 128;
    const size_t nb = (size_t)b * 4096;

    #pragma unroll
    for (int i = 0; i < 4; ++i) {
        const int c = i * 512 + tid;
        const int p = c >> 3, d8 = (c & 7) * 8;
        const uint4 u = *(const uint4*)(kb + ((size_t)(b * 256 + p)) * 256 + h * 64 + d8);
        *(uint4*)&Ks[p * 64 + (d8 ^ ((p & 7) << 3))] = u;
    }
    const short* vsrc = vtb + (size_t)bh * 16384;
    #pragma unroll
    for (int i = 0; i < 4; ++i) {
        const int c = i * 512 + tid;
        const int d = c >> 5, k8 = (c & 31) * 8;
        const uint4 u = *(const uint4*)(vsrc + d * 256 + k8);
        *(uint4*)&Vt[d * 256 + (k8 ^ ((d & 7) << 3))] = u;
    }
    __syncthreads();

    const int w = tid >> 6, lane = tid & 63;
    const int g = lane >> 4, l15 = lane & 15;

    bf16x8 aq[2];
    {
        const int n = q0 + w * 16 + l15;
        const short* qp = qgb + (nb + n) * 256 + h * 64 + g * 8;
        aq[0] = *(const bf16x8*)qp;
        aq[1] = *(const bf16x8*)(qp + 32);
    }

    f32x4 acc[16];
    #pragma unroll
    for (int nt = 0; nt < 16; ++nt) acc[nt] = (f32x4)0.f;

    #pragma unroll
    for (int nt = 0; nt < 16; ++nt) {
        const int key = nt * 16 + l15;
        const int sw = (key & 7) << 3;
        const bf16x8 bk0 = *(const bf16x8*)&Ks[key * 64 + ((g * 8) ^ sw)];
        const bf16x8 bk1 = *(const bf16x8*)&Ks[key * 64 + ((g * 8 + 32) ^ sw)];
        acc[nt] = __builtin_amdgcn_mfma_f32_16x16x32_bf16(aq[0], bk0, acc[nt], 0, 0, 0);
        acc[nt] = __builtin_amdgcn_mfma_f32_16x16x32_bf16(aq[1], bk1, acc[nt], 0, 0, 0);
    }

    float rs[4];
    short* Pw = &Pl[w][0];
    #pragma unroll
    for (int e = 0; e < 4; ++e) {
        const int prow = (g * 4 + e) * CP;
        float rsum = 0.f;
        #pragma unroll
        for (int nt = 0; nt < 16; ++nt) {
            const float p = __expf(acc[nt][e] * SCALE);
            rsum += p;
            Pw[prow + nt * 16 + l15] = (short)f2bf(p);
        }
        rs[e] = rsum;
    }
    #pragma unroll
    for (int e = 0; e < 4; ++e) {
        float v = rs[e];
        v += __shfl_xor(v, 1); v += __shfl_xor(v, 2);
        v += __shfl_xor(v, 4); v += __shfl_xor(v, 8);
        rs[e] = v;
    }

    f32x4 oc[4];
    #pragma unroll
    for (int nt = 0; nt < 4; ++nt) oc[nt] = (f32x4)0.f;

    #pragma unroll
    for (int ks = 0; ks < 8; ++ks) {
        const int kc = ks * 32 + g * 8;
        const bf16x8 a0 = *(const bf16x8*)&Pw[l15 * CP + kc];
        #pragma unroll
        for (int nt = 0; nt < 4; ++nt) {
            const int d = nt * 16 + l15;
            const bf16x8 bv = *(const bf16x8*)&Vt[d * 256 + (kc ^ ((d & 7) << 3))];
            oc[nt] = __builtin_amdgcn_mfma_f32_16x16x32_bf16(a0, bv, oc[nt], 0, 0, 0);
        }
    }

    #pragma unroll
    for (int e = 0; e < 4; ++e) {
        const float inv = 1.f / rs[e];
        const int n = q0 + w * 16 + g * 4 + e;
        const size_t base = (nb + n) * 256 + h * 64;
        #pragma unroll
        for (int nt = 0; nt < 4; ++nt) {
            const int d = nt * 16 + l15;
            gxb[base + d] = (short)f2bf(oc[nt][e] * inv + bf2f(lnb[base + d]));
        }
    }
}

// ---------------------------------------------------------------------------
extern "C" void kernel_launch(void* const* d_in, const int* in_sizes, int n_in,
                              void* d_out, int out_size, void* d_ws, size_t ws_size,
                              hipStream_t stream)
{
    (void)in_sizes; (void)n_in; (void)out_size; (void)ws_size;
    const float* x     = (const float*)d_in[0];
    const float* wqkv  = (const float*)d_in[1];
    const float* bqkv  = (const float*)d_in[2];
    const float* wq    = (const float*)d_in[3];
    const float* bq    = (const float*)d_in[4];
    const float* wkv   = (const float*)d_in[5];
    const float* bkv   = (const float*)d_in[6];
    const float* wproj = (const float*)d_in[7];
    const float* bproj = (const float*)d_in[8];
    const float* gnw   = (const float*)d_in[9];
    const float* gnb   = (const float*)d_in[10];
    float* out = (float*)d_out;

    char* wsb = (char*)d_ws;
    short* wb      = (short*)(wsb + 0);            // cast weights (bf16)
    short* qkvb    = (short*)(wsb + 1048576);      // 65536 x 768 (Q,K,V)
    short* lnb     = (short*)(wsb + 101711872);    // 65536 x 256
    short* qgb     = (short*)(wsb + 135266304);    // 65536 x 256
    short* kb      = (short*)(wsb + 168820736);    // 4096 x 256 (K)
    short* vtb     = (short*)(wsb + 170917888);    // 64bh x 64d x 256p (V^T)
    short* pooledb = (short*)(wsb + 173015040);    // 4096 x 256
    short* gxb     = (short*)(wsb + 175112192);    // 65536 x 256 bf16
    short* vwb     = gxb;                          // vwb aliases gxb (disjoint lifetime)
    short* xb      = (short*)(wsb + 208666624);    // 65536 x 256 bf16 (x cast)

    k_castw<<<dim3(224),  dim3(256), 0, stream>>>(wqkv, wq, wkv, wproj, wb);
    k_castx<<<dim3(8192), dim3(256), 0, stream>>>(x, xb);
    // qkv = x @ Wqkv^T + b            (65536 x 768, K=256)
    k_gemm<1><<<dim3(3072), dim3(256), 0, stream>>>(xb, wb, bqkv, qkvb, nullptr, 768, 6);
    // V transpose per (window, head): qkvb -> vwb
    k_vtr<<<dim3(4096), dim3(256), 0, stream>>>(qkvb, vwb);
    // window attention + LN + pool (MFMA)
    k_win3<<<dim3(4096), dim3(256), 0, stream>>>(qkvb, vwb, xb, gnw, gnb, lnb, pooledb);
    // qg = ln @ Wq^T + b              (65536 x 256)
    k_gemm<1><<<dim3(1024), dim3(256), 0, stream>>>(lnb, wb + 196608, bq, qgb, nullptr, 256, 2);
    // kv = pooled @ Wkv^T + b, split K / V^T
    k_gemm<2><<<dim3(128), dim3(256), 0, stream>>>(pooledb, wb + 262144, bkv, kb, vtb, 512, 4);
    // pooled global attention + residual (MFMA)
    k_glb<<<dim3(2048), dim3(512), 0, stream>>>(qgb, kb, vtb, lnb, gxb);
    // out = gx @ Wproj^T + b          (65536 x 256, f32 out)
    k_gemm<0><<<dim3(1024), dim3(256), 0, stream>>>(gxb, wb + 393216, bproj, out, nullptr, 256, 2);
}

// Round 9
// 198.452 us; speedup vs baseline: 1.2194x; 1.0709x over previous
//
#include <hip/hip_runtime.h>
#include <cstddef>

#define SCALE 0.125f
#define LN_EPS 1e-6f

typedef __attribute__((ext_vector_type(8))) short bf16x8;
typedef __attribute__((ext_vector_type(4))) float f32x4;

__device__ __forceinline__ unsigned short f2bf(float f) {
    unsigned u = __float_as_uint(f);
    return (unsigned short)((u + 0x7FFFu + ((u >> 16) & 1u)) >> 16);
}
__device__ __forceinline__ unsigned pack2(float a, float b) {
    return (unsigned)f2bf(a) | ((unsigned)f2bf(b) << 16);
}
__device__ __forceinline__ float bflo(unsigned v) { return __uint_as_float(v << 16); }
__device__ __forceinline__ float bfhi(unsigned v) { return __uint_as_float(v & 0xFFFF0000u); }
__device__ __forceinline__ float bf2f(short s) { return __uint_as_float(((unsigned)(unsigned short)s) << 16); }

#define GLOAD16(gp, lp) __builtin_amdgcn_global_load_lds( \
    (const __attribute__((address_space(1))) void*)(gp),  \
    (__attribute__((address_space(3))) void*)(lp), 16, 0, 0)

// ---------------------------------------------------------------------------
// Cast all 4 weight matrices f32 -> bf16 into wb.
// ---------------------------------------------------------------------------
__global__ __launch_bounds__(256) void k_castw(
    const float* __restrict__ wqkv, const float* __restrict__ wq,
    const float* __restrict__ wkv, const float* __restrict__ wproj,
    short* __restrict__ wb)
{
    const int blk = blockIdx.x;
    const float* src; size_t so, doff;
    if (blk < 96)       { src = wqkv;  so = (size_t)blk * 2048;         doff = 0; }
    else if (blk < 128) { src = wq;    so = (size_t)(blk - 96) * 2048;  doff = 196608; }
    else if (blk < 192) { src = wkv;   so = (size_t)(blk - 128) * 2048; doff = 262144; }
    else                { src = wproj; so = (size_t)(blk - 192) * 2048; doff = 393216; }
    const size_t idx = so + (size_t)threadIdx.x * 8;
    const float4 f0 = *(const float4*)(src + idx);
    const float4 f1 = *(const float4*)(src + idx + 4);
    uint4 o;
    o.x = pack2(f0.x, f0.y); o.y = pack2(f0.z, f0.w);
    o.z = pack2(f1.x, f1.y); o.w = pack2(f1.z, f1.w);
    *(uint4*)(wb + doff + idx) = o;
}

// ---------------------------------------------------------------------------
// Cast x (16.78M f32) -> bf16. 8192 blocks x 2048 elems.
// ---------------------------------------------------------------------------
__global__ __launch_bounds__(256) void k_castx(
    const float* __restrict__ x, short* __restrict__ xb)
{
    const size_t i = ((size_t)blockIdx.x * 256 + threadIdx.x) * 8;
    const float4 f0 = *(const float4*)(x + i);
    const float4 f1 = *(const float4*)(x + i + 4);
    uint4 o;
    o.x = pack2(f0.x, f0.y); o.y = pack2(f0.z, f0.w);
    o.z = pack2(f1.x, f1.y); o.w = pack2(f1.z, f1.w);
    *(uint4*)(xb + i) = o;
}

// ---------------------------------------------------------------------------
// MFMA GEMM: C[M][ldc] = A[M][256] @ Bw[N][256]^T + bias. A, Bw bf16.
// Tile 128x128, BK=64, 4 K-tiles, double-buffered via global_load_lds.
// OUTMODE: 0 = f32 linear (scalar epilogue),
//          1 = bf16 linear (LDS-transposed coalesced epilogue),
//          2 = kv-split: cols<256 -> K row-major; cols>=256 -> V^T per (b,h)
// ---------------------------------------------------------------------------
template<int OUTMODE>
__global__ __launch_bounds__(256, 2) void k_gemm(
    const short* __restrict__ Asrc, const short* __restrict__ Bw,
    const float* __restrict__ bias, void* __restrict__ Cdst,
    short* __restrict__ Vdst, int ldc, int nbn)
{
    __shared__ short Sh[32768];            // As[2] @ 0, Bs[2] @ 16384; Cl reuses
    short* const As0 = Sh;
    short* const Bs0 = Sh + 16384;

    const int tid = threadIdx.x;
    const int q8 = gridDim.x >> 3;
    const int bid = (blockIdx.x & 7) * q8 + (blockIdx.x >> 3);
    const int bm = bid / nbn, bn = bid % nbn;
    const size_t m0 = (size_t)bm * 128, n0 = (size_t)bn * 128;
    const int wid = tid >> 6, lane = tid & 63;
    const int wr = wid >> 1, wc = wid & 1;
    const int g = lane >> 4, r = lane & 15;
    const int rowc = lane >> 3, gran = lane & 7;

    f32x4 acc[4][4];
    #pragma unroll
    for (int mi = 0; mi < 4; ++mi)
        #pragma unroll
        for (int nj = 0; nj < 4; ++nj) acc[mi][nj] = (f32x4)0.f;

    auto STAGE = [&](int kt, int bufi) {
        const int k0 = kt * 64;
        #pragma unroll
        for (int i = 0; i < 4; ++i) {
            const int rbase = wid * 32 + i * 8;
            const int row = rbase + rowc;
            const int sg = gran ^ (row & 7);
            GLOAD16(Asrc + (m0 + row) * 256 + k0 + sg * 8, As0 + bufi * 8192 + rbase * 64);
            GLOAD16(Bw   + (n0 + row) * 256 + k0 + sg * 8, Bs0 + bufi * 8192 + rbase * 64);
        }
    };

    auto COMPUTE = [&](int bufi) {
        const short* A = As0 + bufi * 8192;
        const short* B = Bs0 + bufi * 8192;
        #pragma unroll
        for (int ks = 0; ks < 2; ++ks) {
            const int ke = ks * 32 + g * 8;
            bf16x8 a[4], b[4];
            #pragma unroll
            for (int mi = 0; mi < 4; ++mi) {
                const int row = wr * 64 + mi * 16 + r;
                a[mi] = *(const bf16x8*)&A[row * 64 + (ke ^ ((row & 7) << 3))];
            }
            #pragma unroll
            for (int nj = 0; nj < 4; ++nj) {
                const int row = wc * 64 + nj * 16 + r;
                b[nj] = *(const bf16x8*)&B[row * 64 + (ke ^ ((row & 7) << 3))];
            }
            #pragma unroll
            for (int mi = 0; mi < 4; ++mi)
                #pragma unroll
                for (int nj = 0; nj < 4; ++nj)
                    acc[mi][nj] = __builtin_amdgcn_mfma_f32_16x16x32_bf16(
                        a[mi], b[nj], acc[mi][nj], 0, 0, 0);
        }
    };

    STAGE(0, 0);
    __syncthreads();
    #pragma unroll
    for (int kt = 0; kt < 4; ++kt) {
        const int cur = kt & 1;
        if (kt < 3) STAGE(kt + 1, cur ^ 1);
        COMPUTE(cur);
        __syncthreads();
    }

    if (OUTMODE == 1) {
        // LDS-transposed epilogue: acc -> Cl[128][132] -> coalesced 16B stores
        short* const Cl = Sh;
        #pragma unroll
        for (int nj = 0; nj < 4; ++nj) {
            const int col = wc * 64 + nj * 16 + r;
            const float bv = bias[n0 + col];
            #pragma unroll
            for (int mi = 0; mi < 4; ++mi) {
                const int row = wr * 64 + mi * 16 + g * 4;
                #pragma unroll
                for (int e = 0; e < 4; ++e)
                    Cl[(row + e) * 132 + col] = (short)f2bf(acc[mi][nj][e] + bv);
            }
        }
        __syncthreads();
        short* C = (short*)Cdst;
        #pragma unroll
        for (int j = 0; j < 8; ++j) {
            const int row = j * 16 + (tid >> 4);
            const int c8 = (tid & 15) * 8;
            const uint4 v = *(const uint4*)&Cl[row * 132 + c8];
            *(uint4*)(C + (m0 + row) * ldc + n0 + c8) = v;
        }
    } else {
        #pragma unroll
        for (int nj = 0; nj < 4; ++nj) {
            const size_t col = n0 + wc * 64 + nj * 16 + r;
            const float bv = bias[col];
            #pragma unroll
            for (int mi = 0; mi < 4; ++mi) {
                const size_t row = m0 + wr * 64 + mi * 16 + g * 4;
                #pragma unroll
                for (int e = 0; e < 4; ++e) {
                    const float v = acc[mi][nj][e] + bv;
                    const size_t rr = row + e;
                    if (OUTMODE == 0) ((float*)Cdst)[rr * ldc + col] = v;
                    else {
                        const int colk = (int)col - 256;
                        if (colk < 0) ((short*)Cdst)[rr * 256 + col] = (short)f2bf(v);
                        else {
                            const int hh = colk >> 6, dd = colk & 63;
                            Vdst[((((rr >> 8) * 4 + hh) * 64 + dd) << 8) + (rr & 255)] = (short)f2bf(v);
                        }
                    }
                }
            }
        }
    }
}

// ---------------------------------------------------------------------------
// V transpose: qkvb[n][768] cols 512..767 -> vwb[((b*256+win)*4+h)*64+d][16tok].
// ---------------------------------------------------------------------------
__global__ __launch_bounds__(256) void k_vtr(
    const short* __restrict__ qkvb, short* __restrict__ vwb)
{
    __shared__ short Vl[16][260];
    const int tid = threadIdx.x;
    const int blk = blockIdx.x;              // b*256 + win
    const int b = blk >> 8, win = blk & 255;
    const int ghi = win >> 4, gwi = win & 15;
    const size_t nb = (size_t)b * 4096;

    #pragma unroll
    for (int i = 0; i < 2; ++i) {
        const int c = i * 256 + tid;         // 0..511
        const int tok = c >> 5, ch = c & 31;
        const int n = (ghi * 4 + (tok >> 2)) * 64 + gwi * 4 + (tok & 3);
        const uint4 u = *(const uint4*)(qkvb + (nb + n) * 768 + 512 + ch * 8);
        short* dst = &Vl[tok][ch * 8];
        *(uint2*)dst = make_uint2(u.x, u.y);
        *(uint2*)(dst + 4) = make_uint2(u.z, u.w);
    }
    __syncthreads();

    unsigned w[8];
    #pragma unroll
    for (int k = 0; k < 8; ++k) {
        const unsigned lo = (unsigned)(unsigned short)Vl[2 * k][tid];
        const unsigned hi = (unsigned)(unsigned short)Vl[2 * k + 1][tid];
        w[k] = lo | (hi << 16);
    }
    short* dst = vwb + ((size_t)blk * 256 + tid) * 16;
    *(uint4*)dst = make_uint4(w[0], w[1], w[2], w[3]);
    *(uint4*)(dst + 8) = make_uint4(w[4], w[5], w[6], w[7]);
}

// ---------------------------------------------------------------------------
// Window attention via MFMA + residual + LN + pool (round-8 verified body).
// ---------------------------------------------------------------------------
__global__ __launch_bounds__(256) void k_win3(
    const short* __restrict__ qkvb, const short* __restrict__ vwb,
    const short* __restrict__ xb, const float* __restrict__ gnw,
    const float* __restrict__ gnb, short* __restrict__ lnb,
    short* __restrict__ pooledb)
{
    __shared__ float zbuf[16][260];
    __shared__ short Pb[4][16][40];

    const int tid = threadIdx.x;
    const int blk = blockIdx.x;
    const int b = blk >> 8, win = blk & 255;
    const int ghi = win >> 4, gwi = win & 15;
    const size_t nb = (size_t)b * 4096;
    const int h = tid >> 6, lane = tid & 63;
    const int g = lane >> 4, l15 = lane & 15;

    const int n15 = (ghi * 4 + (l15 >> 2)) * 64 + gwi * 4 + (l15 & 3);
    const size_t qkrow = (nb + n15) * 768;
    const bf16x8 aq0 = *(const bf16x8*)(qkvb + qkrow + h * 64 + g * 8);
    const bf16x8 aq1 = *(const bf16x8*)(qkvb + qkrow + h * 64 + 32 + g * 8);
    const bf16x8 bk0 = *(const bf16x8*)(qkvb + qkrow + 256 + h * 64 + g * 8);
    const bf16x8 bk1 = *(const bf16x8*)(qkvb + qkrow + 256 + h * 64 + 32 + g * 8);

    f32x4 acc = (f32x4)0.f;
    acc = __builtin_amdgcn_mfma_f32_16x16x32_bf16(aq0, bk0, acc, 0, 0, 0);
    acc = __builtin_amdgcn_mfma_f32_16x16x32_bf16(aq1, bk1, acc, 0, 0, 0);

    float p[4];
    #pragma unroll
    for (int e = 0; e < 4; ++e) {
        const float s = acc[e] * SCALE;
        float mm = s;
        mm = fmaxf(mm, __shfl_xor(mm, 1)); mm = fmaxf(mm, __shfl_xor(mm, 2));
        mm = fmaxf(mm, __shfl_xor(mm, 4)); mm = fmaxf(mm, __shfl_xor(mm, 8));
        const float pe = __expf(s - mm);
        float rs = pe;
        rs += __shfl_xor(rs, 1); rs += __shfl_xor(rs, 2);
        rs += __shfl_xor(rs, 4); rs += __shfl_xor(rs, 8);
        p[e] = pe / rs;
    }
    #pragma unroll
    for (int e = 0; e < 4; ++e) {
        Pb[h][g * 4 + e][l15] = (short)f2bf(p[e]);
        Pb[h][g * 4 + e][16 + l15] = 0;
    }
    __syncthreads();

    const bf16x8 ap = *(const bf16x8*)&Pb[h][l15][g * 8];
    f32x4 oc[4];
    #pragma unroll
    for (int nt = 0; nt < 4; ++nt) oc[nt] = (f32x4)0.f;
    const short* vbase = vwb + ((((size_t)b * 256 + win) * 4 + h) << 10);
    #pragma unroll
    for (int nt = 0; nt < 4; ++nt) {
        const bf16x8 bv = *(const bf16x8*)(vbase + (nt * 16 + l15) * 16 + g * 8);
        oc[nt] = __builtin_amdgcn_mfma_f32_16x16x32_bf16(ap, bv, oc[nt], 0, 0, 0);
    }
    #pragma unroll
    for (int e = 0; e < 4; ++e)
        #pragma unroll
        for (int nt = 0; nt < 4; ++nt)
            zbuf[g * 4 + e][h * 64 + nt * 16 + l15] = oc[nt][e];
    __syncthreads();

    {
        const float4 gw = ((const float4*)gnw)[lane];
        const float4 gb = ((const float4*)gnb)[lane];
        #pragma unroll
        for (int i = 0; i < 4; ++i) {
            const int t = h * 4 + i;
            const int n = (ghi * 4 + (t >> 2)) * 64 + gwi * 4 + (t & 3);
            float4 zv = *(const float4*)&zbuf[t][lane * 4];
            const short4 xv = *(const short4*)(xb + (nb + n) * 256 + lane * 4);
            zv.x += bf2f(xv.x); zv.y += bf2f(xv.y);
            zv.z += bf2f(xv.z); zv.w += bf2f(xv.w);
            float ssum = zv.x + zv.y + zv.z + zv.w;
            for (int off = 1; off < 64; off <<= 1) ssum += __shfl_xor(ssum, off);
            const float u = ssum * (1.f / 256.f);
            const float dx = zv.x - u, dy = zv.y - u, dz = zv.z - u, dw = zv.w - u;
            float vsum = dx * dx + dy * dy + dz * dz + dw * dw;
            for (int off = 1; off < 64; off <<= 1) vsum += __shfl_xor(vsum, off);
            const float rinv = rsqrtf(vsum * (1.f / 256.f) + LN_EPS);
            float4 y;
            y.x = gw.x * dx * rinv + gb.x;
            y.y = gw.y * dy * rinv + gb.y;
            y.z = gw.z * dz * rinv + gb.z;
            y.w = gw.w * dw * rinv + gb.w;
            *(float4*)&zbuf[t][lane * 4] = y;
            short4 sv;
            sv.x = (short)f2bf(y.x); sv.y = (short)f2bf(y.y);
            sv.z = (short)f2bf(y.z); sv.w = (short)f2bf(y.w);
            *(short4*)(lnb + (nb + n) * 256 + lane * 4) = sv;
        }
    }
    __syncthreads();

    {
        float ps = 0.f;
        #pragma unroll
        for (int t = 0; t < 16; ++t) ps += zbuf[t][tid];
        pooledb[((size_t)b * 256 + win) * 256 + tid] = (short)f2bf(ps * (1.f / 16.f));
    }
}

// ---------------------------------------------------------------------------
// Pooled global attention via MFMA, 2-chunk flash (128 keys/chunk).
// 512 threads / 8 waves, 16 q-rows per wave. LDS 66.6KB -> 2 blocks/CU.
// K chunk [128][64] swz + V^T chunk [64][128] swz + P [8][16][136].
// oc / rs accumulate across chunks (no max-sub; purely additive).
// ---------------------------------------------------------------------------
#define CP 136
__global__ __launch_bounds__(512, 4) void k_glb(
    const short* __restrict__ qgb, const short* __restrict__ kb,
    const short* __restrict__ vtb, const short* __restrict__ lnb,
    short* __restrict__ gxb)
{
    __shared__ short Ks[128 * 64];
    __shared__ short Vt[64 * 128];
    __shared__ short Pl[8][16 * CP];

    const int tid = threadIdx.x;
    const int bid = (blockIdx.x & 7) * 256 + (blockIdx.x >> 3);
    const int bh = bid >> 5, qt = bid & 31;
    const int b = bh >> 2, h = bh & 3;
    const int q0 = qt * 128;
    const size_t nb = (size_t)b * 4096;

    const int w = tid >> 6, lane = tid & 63;
    const int g = lane >> 4, l15 = lane & 15;

    // Q A-fragments from global (wave w owns q-rows q0+w*16..+15)
    bf16x8 aq[2];
    {
        const int n = q0 + w * 16 + l15;
        const short* qp = qgb + (nb + n) * 256 + h * 64 + g * 8;
        aq[0] = *(const bf16x8*)qp;
        aq[1] = *(const bf16x8*)(qp + 32);
    }

    f32x4 oc[4];
    #pragma unroll
    for (int nt = 0; nt < 4; ++nt) oc[nt] = (f32x4)0.f;
    float rs[4] = {0.f, 0.f, 0.f, 0.f};

    const short* ksrc = kb + ((size_t)b * 256) * 256 + h * 64;
    const short* vsrc = vtb + (size_t)bh * 16384;
    short* Pw = &Pl[w][0];

    for (int c = 0; c < 2; ++c) {
        if (c) __syncthreads();   // all waves done reading chunk-0 K/V
        // stage K chunk: 128 keys x 64 d (1024 granules / 512 threads)
        #pragma unroll
        for (int i = 0; i < 2; ++i) {
            const int cc = i * 512 + tid;
            const int p = cc >> 3, d8 = (cc & 7) * 8;
            const uint4 u = *(const uint4*)(ksrc + (size_t)(c * 128 + p) * 256 + d8);
            *(uint4*)&Ks[p * 64 + (d8 ^ ((p & 7) << 3))] = u;
        }
        // stage V^T chunk: 64 d x 128 keys
        #pragma unroll
        for (int i = 0; i < 2; ++i) {
            const int cc = i * 512 + tid;
            const int d = cc >> 4, k8 = (cc & 15) * 8;
            const uint4 u = *(const uint4*)(vsrc + d * 256 + c * 128 + k8);
            *(uint4*)&Vt[d * 128 + (k8 ^ ((d & 7) << 3))] = u;
        }
        __syncthreads();

        // S = Q K^T over this chunk's 128 keys
        f32x4 acc[8];
        #pragma unroll
        for (int nt = 0; nt < 8; ++nt) acc[nt] = (f32x4)0.f;
        #pragma unroll
        for (int nt = 0; nt < 8; ++nt) {
            const int key = nt * 16 + l15;
            const int sw = (key & 7) << 3;
            const bf16x8 bk0 = *(const bf16x8*)&Ks[key * 64 + ((g * 8) ^ sw)];
            const bf16x8 bk1 = *(const bf16x8*)&Ks[key * 64 + ((g * 8 + 32) ^ sw)];
            acc[nt] = __builtin_amdgcn_mfma_f32_16x16x32_bf16(aq[0], bk0, acc[nt], 0, 0, 0);
            acc[nt] = __builtin_amdgcn_mfma_f32_16x16x32_bf16(aq[1], bk1, acc[nt], 0, 0, 0);
        }

        // exp (no max-sub), unnormalized P -> LDS, row-sum partials
        #pragma unroll
        for (int e = 0; e < 4; ++e) {
            const int prow = (g * 4 + e) * CP;
            float rsum = 0.f;
            #pragma unroll
            for (int nt = 0; nt < 8; ++nt) {
                const float p = __expf(acc[nt][e] * SCALE);
                rsum += p;
                Pw[prow + nt * 16 + l15] = (short)f2bf(p);
            }
            rs[e] += rsum;
        }

        // O += P V over this chunk (4 K-steps of 32)
        #pragma unroll
        for (int ks = 0; ks < 4; ++ks) {
            const int kc = ks * 32 + g * 8;
            const bf16x8 a0 = *(const bf16x8*)&Pw[l15 * CP + kc];
            #pragma unroll
            for (int nt = 0; nt < 4; ++nt) {
                const int d = nt * 16 + l15;
                const bf16x8 bv = *(const bf16x8*)&Vt[d * 128 + (kc ^ ((d & 7) << 3))];
                oc[nt] = __builtin_amdgcn_mfma_f32_16x16x32_bf16(a0, bv, oc[nt], 0, 0, 0);
            }
        }
    }

    // reduce row-sums across the 16 lanes holding each row's keys
    #pragma unroll
    for (int e = 0; e < 4; ++e) {
        float v = rs[e];
        v += __shfl_xor(v, 1); v += __shfl_xor(v, 2);
        v += __shfl_xor(v, 4); v += __shfl_xor(v, 8);
        rs[e] = v;
    }

    // epilogue: normalize, residual, bf16 store
    #pragma unroll
    for (int e = 0; e < 4; ++e) {
        const float inv = 1.f / rs[e];
        const int n = q0 + w * 16 + g * 4 + e;
        const size_t base = (nb + n) * 256 + h * 64;
        #pragma unroll
        for (int nt = 0; nt < 4; ++nt) {
            const int d = nt * 16 + l15;
            gxb[base + d] = (short)f2bf(oc[nt][e] * inv + bf2f(lnb[base + d]));
        }
    }
}

// ---------------------------------------------------------------------------
extern "C" void kernel_launch(void* const* d_in, const int* in_sizes, int n_in,
                              void* d_out, int out_size, void* d_ws, size_t ws_size,
                              hipStream_t stream)
{
    (void)in_sizes; (void)n_in; (void)out_size; (void)ws_size;
    const float* x     = (const float*)d_in[0];
    const float* wqkv  = (const float*)d_in[1];
    const float* bqkv  = (const float*)d_in[2];
    const float* wq    = (const float*)d_in[3];
    const float* bq    = (const float*)d_in[4];
    const float* wkv   = (const float*)d_in[5];
    const float* bkv   = (const float*)d_in[6];
    const float* wproj = (const float*)d_in[7];
    const float* bproj = (const float*)d_in[8];
    const float* gnw   = (const float*)d_in[9];
    const float* gnb   = (const float*)d_in[10];
    float* out = (float*)d_out;

    char* wsb = (char*)d_ws;
    short* wb      = (short*)(wsb + 0);            // cast weights (bf16)
    short* qkvb    = (short*)(wsb + 1048576);      // 65536 x 768 (Q,K,V)
    short* lnb     = (short*)(wsb + 101711872);    // 65536 x 256
    short* qgb     = (short*)(wsb + 135266304);    // 65536 x 256
    short* kb      = (short*)(wsb + 168820736);    // 4096 x 256 (K)
    short* vtb     = (short*)(wsb + 170917888);    // 64bh x 64d x 256p (V^T)
    short* pooledb = (short*)(wsb + 173015040);    // 4096 x 256
    short* gxb     = (short*)(wsb + 175112192);    // 65536 x 256 bf16
    short* vwb     = gxb;                          // vwb aliases gxb (disjoint lifetime)
    short* xb      = (short*)(wsb + 208666624);    // 65536 x 256 bf16 (x cast)

    k_castw<<<dim3(224),  dim3(256), 0, stream>>>(wqkv, wq, wkv, wproj, wb);
    k_castx<<<dim3(8192), dim3(256), 0, stream>>>(x, xb);
    // qkv = x @ Wqkv^T + b            (65536 x 768, K=256)
    k_gemm<1><<<dim3(3072), dim3(256), 0, stream>>>(xb, wb, bqkv, qkvb, nullptr, 768, 6);
    // V transpose per (window, head): qkvb -> vwb
    k_vtr<<<dim3(4096), dim3(256), 0, stream>>>(qkvb, vwb);
    // window attention + LN + pool (MFMA)
    k_win3<<<dim3(4096), dim3(256), 0, stream>>>(qkvb, vwb, xb, gnw, gnb, lnb, pooledb);
    // qg = ln @ Wq^T + b              (65536 x 256)
    k_gemm<1><<<dim3(1024), dim3(256), 0, stream>>>(lnb, wb + 196608, bq, qgb, nullptr, 256, 2);
    // kv = pooled @ Wkv^T + b, split K / V^T
    k_gemm<2><<<dim3(128), dim3(256), 0, stream>>>(pooledb, wb + 262144, bkv, kb, vtb, 512, 4);
    // pooled global attention + residual (MFMA, 2-chunk flash)
    k_glb<<<dim3(2048), dim3(512), 0, stream>>>(qgb, kb, vtb, lnb, gxb);
    // out = gx @ Wproj^T + b          (65536 x 256, f32 out)
    k_gemm<0><<<dim3(1024), dim3(256), 0, stream>>>(gxb, wb + 393216, bproj, out, nullptr, 256, 2);
}

// Round 10
// 193.306 us; speedup vs baseline: 1.2519x; 1.0266x over previous
//
#include <hip/hip_runtime.h>
#include <cstddef>

#define SCALE 0.125f
#define LN_EPS 1e-6f

typedef __attribute__((ext_vector_type(8))) short bf16x8;
typedef __attribute__((ext_vector_type(4))) float f32x4;

__device__ __forceinline__ unsigned short f2bf(float f) {
    unsigned u = __float_as_uint(f);
    return (unsigned short)((u + 0x7FFFu + ((u >> 16) & 1u)) >> 16);
}
__device__ __forceinline__ unsigned pack2(float a, float b) {
    return (unsigned)f2bf(a) | ((unsigned)f2bf(b) << 16);
}
__device__ __forceinline__ float bflo(unsigned v) { return __uint_as_float(v << 16); }
__device__ __forceinline__ float bfhi(unsigned v) { return __uint_as_float(v & 0xFFFF0000u); }
__device__ __forceinline__ float bf2f(short s) { return __uint_as_float(((unsigned)(unsigned short)s) << 16); }

#define GLOAD16(gp, lp) __builtin_amdgcn_global_load_lds( \
    (const __attribute__((address_space(1))) void*)(gp),  \
    (__attribute__((address_space(3))) void*)(lp), 16, 0, 0)

// ---------------------------------------------------------------------------
// Cast all 4 weight matrices f32 -> bf16 into wb.
// ---------------------------------------------------------------------------
__global__ __launch_bounds__(256) void k_castw(
    const float* __restrict__ wqkv, const float* __restrict__ wq,
    const float* __restrict__ wkv, const float* __restrict__ wproj,
    short* __restrict__ wb)
{
    const int blk = blockIdx.x;
    const float* src; size_t so, doff;
    if (blk < 96)       { src = wqkv;  so = (size_t)blk * 2048;         doff = 0; }
    else if (blk < 128) { src = wq;    so = (size_t)(blk - 96) * 2048;  doff = 196608; }
    else if (blk < 192) { src = wkv;   so = (size_t)(blk - 128) * 2048; doff = 262144; }
    else                { src = wproj; so = (size_t)(blk - 192) * 2048; doff = 393216; }
    const size_t idx = so + (size_t)threadIdx.x * 8;
    const float4 f0 = *(const float4*)(src + idx);
    const float4 f1 = *(const float4*)(src + idx + 4);
    uint4 o;
    o.x = pack2(f0.x, f0.y); o.y = pack2(f0.z, f0.w);
    o.z = pack2(f1.x, f1.y); o.w = pack2(f1.z, f1.w);
    *(uint4*)(wb + doff + idx) = o;
}

// ---------------------------------------------------------------------------
// Cast x (16.78M f32) -> bf16. 8192 blocks x 2048 elems.
// ---------------------------------------------------------------------------
__global__ __launch_bounds__(256) void k_castx(
    const float* __restrict__ x, short* __restrict__ xb)
{
    const size_t i = ((size_t)blockIdx.x * 256 + threadIdx.x) * 8;
    const float4 f0 = *(const float4*)(x + i);
    const float4 f1 = *(const float4*)(x + i + 4);
    uint4 o;
    o.x = pack2(f0.x, f0.y); o.y = pack2(f0.z, f0.w);
    o.z = pack2(f1.x, f1.y); o.w = pack2(f1.z, f1.w);
    *(uint4*)(xb + i) = o;
}

// ---------------------------------------------------------------------------
// MFMA GEMM: C[M][ldc] = A[M][256] @ Bw[N][256]^T + bias. A, Bw bf16.
// Tile 128x128, BK=64, 4 K-tiles, SINGLE-buffered LDS (34.8KB incl. epilogue
// scratch) -> 4 blocks/CU; inter-block overlap hides stage latency.
// Staged via global_load_lds (linear dest, XOR-swizzled source granule).
// OUTMODE: 0 = f32 linear (scalar epilogue),
//          1 = bf16 linear (LDS-transposed coalesced epilogue),
//          2 = kv-split: cols<256 -> K row-major; cols>=256 -> V^T per (b,h)
// ---------------------------------------------------------------------------
template<int OUTMODE>
__global__ __launch_bounds__(256, 4) void k_gemm(
    const short* __restrict__ Asrc, const short* __restrict__ Bw,
    const float* __restrict__ bias, void* __restrict__ Cdst,
    short* __restrict__ Vdst, int ldc, int nbn)
{
    __shared__ short Sh[17408];            // As @ 0 (16KB), Bs @ 8192 (16KB); Cl reuses
    short* const As0 = Sh;
    short* const Bs0 = Sh + 8192;

    const int tid = threadIdx.x;
    const int q8 = gridDim.x >> 3;
    const int bid = (blockIdx.x & 7) * q8 + (blockIdx.x >> 3);
    const int bm = bid / nbn, bn = bid % nbn;
    const size_t m0 = (size_t)bm * 128, n0 = (size_t)bn * 128;
    const int wid = tid >> 6, lane = tid & 63;
    const int wr = wid >> 1, wc = wid & 1;
    const int g = lane >> 4, r = lane & 15;
    const int rowc = lane >> 3, gran = lane & 7;

    f32x4 acc[4][4];
    #pragma unroll
    for (int mi = 0; mi < 4; ++mi)
        #pragma unroll
        for (int nj = 0; nj < 4; ++nj) acc[mi][nj] = (f32x4)0.f;

    auto STAGE = [&](int kt) {
        const int k0 = kt * 64;
        #pragma unroll
        for (int i = 0; i < 4; ++i) {
            const int rbase = wid * 32 + i * 8;
            const int row = rbase + rowc;
            const int sg = gran ^ (row & 7);
            GLOAD16(Asrc + (m0 + row) * 256 + k0 + sg * 8, As0 + rbase * 64);
            GLOAD16(Bw   + (n0 + row) * 256 + k0 + sg * 8, Bs0 + rbase * 64);
        }
    };

    auto COMPUTE = [&]() {
        #pragma unroll
        for (int ks = 0; ks < 2; ++ks) {
            const int ke = ks * 32 + g * 8;
            bf16x8 a[4], b[4];
            #pragma unroll
            for (int mi = 0; mi < 4; ++mi) {
                const int row = wr * 64 + mi * 16 + r;
                a[mi] = *(const bf16x8*)&As0[row * 64 + (ke ^ ((row & 7) << 3))];
            }
            #pragma unroll
            for (int nj = 0; nj < 4; ++nj) {
                const int row = wc * 64 + nj * 16 + r;
                b[nj] = *(const bf16x8*)&Bs0[row * 64 + (ke ^ ((row & 7) << 3))];
            }
            #pragma unroll
            for (int mi = 0; mi < 4; ++mi)
                #pragma unroll
                for (int nj = 0; nj < 4; ++nj)
                    acc[mi][nj] = __builtin_amdgcn_mfma_f32_16x16x32_bf16(
                        a[mi], b[nj], acc[mi][nj], 0, 0, 0);
        }
    };

    #pragma unroll
    for (int kt = 0; kt < 4; ++kt) {
        STAGE(kt);
        __syncthreads();       // drains gload_lds (vmcnt) before reads
        COMPUTE();
        __syncthreads();       // all waves done reading before next overwrite
    }

    if (OUTMODE == 1) {
        // LDS-transposed epilogue: acc -> Cl[128][136] -> coalesced 16B stores
        short* const Cl = Sh;
        #pragma unroll
        for (int nj = 0; nj < 4; ++nj) {
            const int col = wc * 64 + nj * 16 + r;
            const float bv = bias[n0 + col];
            #pragma unroll
            for (int mi = 0; mi < 4; ++mi) {
                const int row = wr * 64 + mi * 16 + g * 4;
                #pragma unroll
                for (int e = 0; e < 4; ++e)
                    Cl[(row + e) * 136 + col] = (short)f2bf(acc[mi][nj][e] + bv);
            }
        }
        __syncthreads();
        short* C = (short*)Cdst;
        #pragma unroll
        for (int j = 0; j < 8; ++j) {
            const int row = j * 16 + (tid >> 4);
            const int c8 = (tid & 15) * 8;
            const uint4 v = *(const uint4*)&Cl[row * 136 + c8];
            *(uint4*)(C + (m0 + row) * ldc + n0 + c8) = v;
        }
    } else {
        #pragma unroll
        for (int nj = 0; nj < 4; ++nj) {
            const size_t col = n0 + wc * 64 + nj * 16 + r;
            const float bv = bias[col];
            #pragma unroll
            for (int mi = 0; mi < 4; ++mi) {
                const size_t row = m0 + wr * 64 + mi * 16 + g * 4;
                #pragma unroll
                for (int e = 0; e < 4; ++e) {
                    const float v = acc[mi][nj][e] + bv;
                    const size_t rr = row + e;
                    if (OUTMODE == 0) ((float*)Cdst)[rr * ldc + col] = v;
                    else {
                        const int colk = (int)col - 256;
                        if (colk < 0) ((short*)Cdst)[rr * 256 + col] = (short)f2bf(v);
                        else {
                            const int hh = colk >> 6, dd = colk & 63;
                            Vdst[((((rr >> 8) * 4 + hh) * 64 + dd) << 8) + (rr & 255)] = (short)f2bf(v);
                        }
                    }
                }
            }
        }
    }
}

// ---------------------------------------------------------------------------
// V transpose: qkvb[n][768] cols 512..767 -> vwb[((b*256+win)*4+h)*64+d][16tok].
// ---------------------------------------------------------------------------
__global__ __launch_bounds__(256) void k_vtr(
    const short* __restrict__ qkvb, short* __restrict__ vwb)
{
    __shared__ short Vl[16][260];
    const int tid = threadIdx.x;
    const int blk = blockIdx.x;              // b*256 + win
    const int b = blk >> 8, win = blk & 255;
    const int ghi = win >> 4, gwi = win & 15;
    const size_t nb = (size_t)b * 4096;

    #pragma unroll
    for (int i = 0; i < 2; ++i) {
        const int c = i * 256 + tid;         // 0..511
        const int tok = c >> 5, ch = c & 31;
        const int n = (ghi * 4 + (tok >> 2)) * 64 + gwi * 4 + (tok & 3);
        const uint4 u = *(const uint4*)(qkvb + (nb + n) * 768 + 512 + ch * 8);
        short* dst = &Vl[tok][ch * 8];
        *(uint2*)dst = make_uint2(u.x, u.y);
        *(uint2*)(dst + 4) = make_uint2(u.z, u.w);
    }
    __syncthreads();

    unsigned w[8];
    #pragma unroll
    for (int k = 0; k < 8; ++k) {
        const unsigned lo = (unsigned)(unsigned short)Vl[2 * k][tid];
        const unsigned hi = (unsigned)(unsigned short)Vl[2 * k + 1][tid];
        w[k] = lo | (hi << 16);
    }
    short* dst = vwb + ((size_t)blk * 256 + tid) * 16;
    *(uint4*)dst = make_uint4(w[0], w[1], w[2], w[3]);
    *(uint4*)(dst + 8) = make_uint4(w[4], w[5], w[6], w[7]);
}

// ---------------------------------------------------------------------------
// Window attention via MFMA + residual + LN + pool (verified body).
// ---------------------------------------------------------------------------
__global__ __launch_bounds__(256) void k_win3(
    const short* __restrict__ qkvb, const short* __restrict__ vwb,
    const short* __restrict__ xb, const float* __restrict__ gnw,
    const float* __restrict__ gnb, short* __restrict__ lnb,
    short* __restrict__ pooledb)
{
    __shared__ float zbuf[16][260];
    __shared__ short Pb[4][16][40];

    const int tid = threadIdx.x;
    const int blk = blockIdx.x;
    const int b = blk >> 8, win = blk & 255;
    const int ghi = win >> 4, gwi = win & 15;
    const size_t nb = (size_t)b * 4096;
    const int h = tid >> 6, lane = tid & 63;
    const int g = lane >> 4, l15 = lane & 15;

    const int n15 = (ghi * 4 + (l15 >> 2)) * 64 + gwi * 4 + (l15 & 3);
    const size_t qkrow = (nb + n15) * 768;
    const bf16x8 aq0 = *(const bf16x8*)(qkvb + qkrow + h * 64 + g * 8);
    const bf16x8 aq1 = *(const bf16x8*)(qkvb + qkrow + h * 64 + 32 + g * 8);
    const bf16x8 bk0 = *(const bf16x8*)(qkvb + qkrow + 256 + h * 64 + g * 8);
    const bf16x8 bk1 = *(const bf16x8*)(qkvb + qkrow + 256 + h * 64 + 32 + g * 8);

    f32x4 acc = (f32x4)0.f;
    acc = __builtin_amdgcn_mfma_f32_16x16x32_bf16(aq0, bk0, acc, 0, 0, 0);
    acc = __builtin_amdgcn_mfma_f32_16x16x32_bf16(aq1, bk1, acc, 0, 0, 0);

    float p[4];
    #pragma unroll
    for (int e = 0; e < 4; ++e) {
        const float s = acc[e] * SCALE;
        float mm = s;
        mm = fmaxf(mm, __shfl_xor(mm, 1)); mm = fmaxf(mm, __shfl_xor(mm, 2));
        mm = fmaxf(mm, __shfl_xor(mm, 4)); mm = fmaxf(mm, __shfl_xor(mm, 8));
        const float pe = __expf(s - mm);
        float rs = pe;
        rs += __shfl_xor(rs, 1); rs += __shfl_xor(rs, 2);
        rs += __shfl_xor(rs, 4); rs += __shfl_xor(rs, 8);
        p[e] = pe / rs;
    }
    #pragma unroll
    for (int e = 0; e < 4; ++e) {
        Pb[h][g * 4 + e][l15] = (short)f2bf(p[e]);
        Pb[h][g * 4 + e][16 + l15] = 0;
    }
    __syncthreads();

    const bf16x8 ap = *(const bf16x8*)&Pb[h][l15][g * 8];
    f32x4 oc[4];
    #pragma unroll
    for (int nt = 0; nt < 4; ++nt) oc[nt] = (f32x4)0.f;
    const short* vbase = vwb + ((((size_t)b * 256 + win) * 4 + h) << 10);
    #pragma unroll
    for (int nt = 0; nt < 4; ++nt) {
        const bf16x8 bv = *(const bf16x8*)(vbase + (nt * 16 + l15) * 16 + g * 8);
        oc[nt] = __builtin_amdgcn_mfma_f32_16x16x32_bf16(ap, bv, oc[nt], 0, 0, 0);
    }
    #pragma unroll
    for (int e = 0; e < 4; ++e)
        #pragma unroll
        for (int nt = 0; nt < 4; ++nt)
            zbuf[g * 4 + e][h * 64 + nt * 16 + l15] = oc[nt][e];
    __syncthreads();

    {
        const float4 gw = ((const float4*)gnw)[lane];
        const float4 gb = ((const float4*)gnb)[lane];
        #pragma unroll
        for (int i = 0; i < 4; ++i) {
            const int t = h * 4 + i;
            const int n = (ghi * 4 + (t >> 2)) * 64 + gwi * 4 + (t & 3);
            float4 zv = *(const float4*)&zbuf[t][lane * 4];
            const short4 xv = *(const short4*)(xb + (nb + n) * 256 + lane * 4);
            zv.x += bf2f(xv.x); zv.y += bf2f(xv.y);
            zv.z += bf2f(xv.z); zv.w += bf2f(xv.w);
            float ssum = zv.x + zv.y + zv.z + zv.w;
            for (int off = 1; off < 64; off <<= 1) ssum += __shfl_xor(ssum, off);
            const float u = ssum * (1.f / 256.f);
            const float dx = zv.x - u, dy = zv.y - u, dz = zv.z - u, dw = zv.w - u;
            float vsum = dx * dx + dy * dy + dz * dz + dw * dw;
            for (int off = 1; off < 64; off <<= 1) vsum += __shfl_xor(vsum, off);
            const float rinv = rsqrtf(vsum * (1.f / 256.f) + LN_EPS);
            float4 y;
            y.x = gw.x * dx * rinv + gb.x;
            y.y = gw.y * dy * rinv + gb.y;
            y.z = gw.z * dz * rinv + gb.z;
            y.w = gw.w * dw * rinv + gb.w;
            *(float4*)&zbuf[t][lane * 4] = y;
            short4 sv;
            sv.x = (short)f2bf(y.x); sv.y = (short)f2bf(y.y);
            sv.z = (short)f2bf(y.z); sv.w = (short)f2bf(y.w);
            *(short4*)(lnb + (nb + n) * 256 + lane * 4) = sv;
        }
    }
    __syncthreads();

    {
        float ps = 0.f;
        #pragma unroll
        for (int t = 0; t < 16; ++t) ps += zbuf[t][tid];
        pooledb[((size_t)b * 256 + win) * 256 + tid] = (short)f2bf(ps * (1.f / 16.f));
    }
}

// ---------------------------------------------------------------------------
// Pooled global attention via MFMA, 2-chunk flash (128 keys/chunk).
// 512 threads / 8 waves, LDS 66.6KB -> 2 blocks/CU.
// ---------------------------------------------------------------------------
#define CP 136
__global__ __launch_bounds__(512, 4) void k_glb(
    const short* __restrict__ qgb, const short* __restrict__ kb,
    const short* __restrict__ vtb, const short* __restrict__ lnb,
    short* __restrict__ gxb)
{
    __shared__ short Ks[128 * 64];
    __shared__ short Vt[64 * 128];
    __shared__ short Pl[8][16 * CP];

    const int tid = threadIdx.x;
    const int bid = (blockIdx.x & 7) * 256 + (blockIdx.x >> 3);
    const int bh = bid >> 5, qt = bid & 31;
    const int b = bh >> 2, h = bh & 3;
    const int q0 = qt * 128;
    const size_t nb = (size_t)b * 4096;

    const int w = tid >> 6, lane = tid & 63;
    const int g = lane >> 4, l15 = lane & 15;

    bf16x8 aq[2];
    {
        const int n = q0 + w * 16 + l15;
        const short* qp = qgb + (nb + n) * 256 + h * 64 + g * 8;
        aq[0] = *(const bf16x8*)qp;
        aq[1] = *(const bf16x8*)(qp + 32);
    }

    f32x4 oc[4];
    #pragma unroll
    for (int nt = 0; nt < 4; ++nt) oc[nt] = (f32x4)0.f;
    float rs[4] = {0.f, 0.f, 0.f, 0.f};

    const short* ksrc = kb + ((size_t)b * 256) * 256 + h * 64;
    const short* vsrc = vtb + (size_t)bh * 16384;
    short* Pw = &Pl[w][0];

    for (int c = 0; c < 2; ++c) {
        if (c) __syncthreads();
        #pragma unroll
        for (int i = 0; i < 2; ++i) {
            const int cc = i * 512 + tid;
            const int p = cc >> 3, d8 = (cc & 7) * 8;
            const uint4 u = *(const uint4*)(ksrc + (size_t)(c * 128 + p) * 256 + d8);
            *(uint4*)&Ks[p * 64 + (d8 ^ ((p & 7) << 3))] = u;
        }
        #pragma unroll
        for (int i = 0; i < 2; ++i) {
            const int cc = i * 512 + tid;
            const int d = cc >> 4, k8 = (cc & 15) * 8;
            const uint4 u = *(const uint4*)(vsrc + d * 256 + c * 128 + k8);
            *(uint4*)&Vt[d * 128 + (k8 ^ ((d & 7) << 3))] = u;
        }
        __syncthreads();

        f32x4 acc[8];
        #pragma unroll
        for (int nt = 0; nt < 8; ++nt) acc[nt] = (f32x4)0.f;
        #pragma unroll
        for (int nt = 0; nt < 8; ++nt) {
            const int key = nt * 16 + l15;
            const int sw = (key & 7) << 3;
            const bf16x8 bk0 = *(const bf16x8*)&Ks[key * 64 + ((g * 8) ^ sw)];
            const bf16x8 bk1 = *(const bf16x8*)&Ks[key * 64 + ((g * 8 + 32) ^ sw)];
            acc[nt] = __builtin_amdgcn_mfma_f32_16x16x32_bf16(aq[0], bk0, acc[nt], 0, 0, 0);
            acc[nt] = __builtin_amdgcn_mfma_f32_16x16x32_bf16(aq[1], bk1, acc[nt], 0, 0, 0);
        }

        #pragma unroll
        for (int e = 0; e < 4; ++e) {
            const int prow = (g * 4 + e) * CP;
            float rsum = 0.f;
            #pragma unroll
            for (int nt = 0; nt < 8; ++nt) {
                const float p = __expf(acc[nt][e] * SCALE);
                rsum += p;
                Pw[prow + nt * 16 + l15] = (short)f2bf(p);
            }
            rs[e] += rsum;
        }

        #pragma unroll
        for (int ks = 0; ks < 4; ++ks) {
            const int kc = ks * 32 + g * 8;
            const bf16x8 a0 = *(const bf16x8*)&Pw[l15 * CP + kc];
            #pragma unroll
            for (int nt = 0; nt < 4; ++nt) {
                const int d = nt * 16 + l15;
                const bf16x8 bv = *(const bf16x8*)&Vt[d * 128 + (kc ^ ((d & 7) << 3))];
                oc[nt] = __builtin_amdgcn_mfma_f32_16x16x32_bf16(a0, bv, oc[nt], 0, 0, 0);
            }
        }
    }

    #pragma unroll
    for (int e = 0; e < 4; ++e) {
        float v = rs[e];
        v += __shfl_xor(v, 1); v += __shfl_xor(v, 2);
        v += __shfl_xor(v, 4); v += __shfl_xor(v, 8);
        rs[e] = v;
    }

    #pragma unroll
    for (int e = 0; e < 4; ++e) {
        const float inv = 1.f / rs[e];
        const int n = q0 + w * 16 + g * 4 + e;
        const size_t base = (nb + n) * 256 + h * 64;
        #pragma unroll
        for (int nt = 0; nt < 4; ++nt) {
            const int d = nt * 16 + l15;
            gxb[base + d] = (short)f2bf(oc[nt][e] * inv + bf2f(lnb[base + d]));
        }
    }
}

// ---------------------------------------------------------------------------
extern "C" void kernel_launch(void* const* d_in, const int* in_sizes, int n_in,
                              void* d_out, int out_size, void* d_ws, size_t ws_size,
                              hipStream_t stream)
{
    (void)in_sizes; (void)n_in; (void)out_size; (void)ws_size;
    const float* x     = (const float*)d_in[0];
    const float* wqkv  = (const float*)d_in[1];
    const float* bqkv  = (const float*)d_in[2];
    const float* wq    = (const float*)d_in[3];
    const float* bq    = (const float*)d_in[4];
    const float* wkv   = (const float*)d_in[5];
    const float* bkv   = (const float*)d_in[6];
    const float* wproj = (const float*)d_in[7];
    const float* bproj = (const float*)d_in[8];
    const float* gnw   = (const float*)d_in[9];
    const float* gnb   = (const float*)d_in[10];
    float* out = (float*)d_out;

    char* wsb = (char*)d_ws;
    short* wb      = (short*)(wsb + 0);            // cast weights (bf16)
    short* qkvb    = (short*)(wsb + 1048576);      // 65536 x 768 (Q,K,V)
    short* lnb     = (short*)(wsb + 101711872);    // 65536 x 256
    short* qgb     = (short*)(wsb + 135266304);    // 65536 x 256
    short* kb      = (short*)(wsb + 168820736);    // 4096 x 256 (K)
    short* vtb     = (short*)(wsb + 170917888);    // 64bh x 64d x 256p (V^T)
    short* pooledb = (short*)(wsb + 173015040);    // 4096 x 256
    short* gxb     = (short*)(wsb + 175112192);    // 65536 x 256 bf16
    short* vwb     = gxb;                          // vwb aliases gxb (disjoint lifetime)
    short* xb      = (short*)(wsb + 208666624);    // 65536 x 256 bf16 (x cast)

    k_castw<<<dim3(224),  dim3(256), 0, stream>>>(wqkv, wq, wkv, wproj, wb);
    k_castx<<<dim3(8192), dim3(256), 0, stream>>>(x, xb);
    // qkv = x @ Wqkv^T + b            (65536 x 768, K=256)
    k_gemm<1><<<dim3(3072), dim3(256), 0, stream>>>(xb, wb, bqkv, qkvb, nullptr, 768, 6);
    // V transpose per (window, head): qkvb -> vwb
    k_vtr<<<dim3(4096), dim3(256), 0, stream>>>(qkvb, vwb);
    // window attention + LN + pool (MFMA)
    k_win3<<<dim3(4096), dim3(256), 0, stream>>>(qkvb, vwb, xb, gnw, gnb, lnb, pooledb);
    // qg = ln @ Wq^T + b              (65536 x 256)
    k_gemm<1><<<dim3(1024), dim3(256), 0, stream>>>(lnb, wb + 196608, bq, qgb, nullptr, 256, 2);
    // kv = pooled @ Wkv^T + b, split K / V^T
    k_gemm<2><<<dim3(128), dim3(256), 0, stream>>>(pooledb, wb + 262144, bkv, kb, vtb, 512, 4);
    // pooled global attention + residual (MFMA, 2-chunk flash)
    k_glb<<<dim3(2048), dim3(512), 0, stream>>>(qgb, kb, vtb, lnb, gxb);
    // out = gx @ Wproj^T + b          (65536 x 256, f32 out)
    k_gemm<0><<<dim3(1024), dim3(256), 0, stream>>>(gxb, wb + 393216, bproj, out, nullptr, 256, 2);
}